// Round 9
// baseline (150.826 us; speedup 1.0000x reference)
//
#include <hip/hip_runtime.h>
#include <hip/hip_bf16.h>

// CARAFE fused: B=4, C=128, H=W=64, C_MID=64, S=2, K=5
// ROUND 9 = DIAGNOSTIC: identical to round 8 but the fused body runs twice
// (idempotent) so the kernel exceeds the 44us harness-fill floor and becomes
// visible in rocprof top-5 with counters. Revert rep-loop next round.
#define HW 4096

typedef __attribute__((ext_vector_type(8))) short  short8;   // 8 bf16 (4 VGPRs)
typedef __attribute__((ext_vector_type(4))) float  floatx4;  // MFMA C/D

// workspace (BYTE offsets)
#define OFF_W2B 0ul        // bf16 [112][576]  = 129024 B   w2b[n][k], k = tap*64 + c
#define OFF_W1B 129024ul   // bf16 [64][128]   = 16384 B    w1b[o][c]
#define OFF_BN  145408ul   // float2[64]       = 512 B      (inv, add) per o
#define OFF_XG  145920ul   // bf16 [4][16][4096][8] = 4 MB  x transposed: [b][cq][pix][8c]

__device__ __forceinline__ float bfbits(unsigned u) {
    union { unsigned u; float f; } t; t.u = u; return t.f;
}

// ---------------- prep: x -> bf16 [b][cq][pix][8]; w2 -> bf16 [n][k]; w1 bf16; BN folded ----
__global__ __launch_bounds__(256) void prep_kernel(const float* __restrict__ x,
                                                   const float* __restrict__ w1,
                                                   const float* __restrict__ w2,
                                                   const float* __restrict__ gamma,
                                                   const float* __restrict__ beta,
                                                   const float* __restrict__ mean,
                                                   const float* __restrict__ var,
                                                   char* __restrict__ ws) {
    int tid = blockIdx.x * 256 + threadIdx.x;
    if (tid < 262144) {
        int pix = tid & 4095;
        int cq  = (tid >> 12) & 15;
        int b   = tid >> 16;
        const float* xp = x + ((size_t)(b * 128 + cq * 8)) * HW + pix;
        union { short8 s; __hip_bfloat16 h[8]; } u;
        #pragma unroll
        for (int cc = 0; cc < 8; ++cc) u.h[cc] = __float2bfloat16(xp[(size_t)cc * HW]);
        *(short8*)((__hip_bfloat16*)(ws + OFF_XG) + (size_t)tid * 8) = u.s;
        return;
    }
    int t2 = tid - 262144;
    if (t2 < 64512) {
        int n = t2 / 576;
        int k = t2 - n * 576;        // k = tap*64 + c
        int t = k >> 6, c = k & 63;
        float v = (n < 100) ? w2[(n * 64 + c) * 9 + t] : 0.f;
        ((__hip_bfloat16*)(ws + OFF_W2B))[t2] = __float2bfloat16(v);
    } else if (t2 < 64512 + 8192) {
        int i = t2 - 64512;
        ((__hip_bfloat16*)(ws + OFF_W1B))[i] = __float2bfloat16(w1[i]);
    } else if (t2 < 64512 + 8192 + 64) {
        int o = t2 - 64512 - 8192;
        float inv = gamma[o] * rsqrtf(var[o] + 1e-5f);
        ((float2*)(ws + OFF_BN))[o] = make_float2(inv, beta[o] - mean[o] * inv);
    }
}

// ---------------- fused CARAFE: one block per (b, 4x8 tile), 1024 threads = 16 waves --------
__global__ __launch_bounds__(1024, 8) void fused_carafe(const char* __restrict__ ws,
                                                        float* __restrict__ out) {
    __shared__ __align__(16) __hip_bfloat16 xs[1536 * 8];  // x halo [cq16][pix96][8c], 24.6 KB
    __shared__ __align__(16) __hip_bfloat16 hs[60 * 72];   // h halo 6x10 [pix][c],      8.6 KB
    __shared__ __align__(16) float lg[32 * 114];           // logits [pix][n],          14.6 KB
    __shared__ __align__(16) float ks[100 * 33];           // ker [t*4+g][pix],         13.2 KB

    int b    = blockIdx.x >> 7;
    int tile = blockIdx.x & 127;
    int ty0 = (tile >> 3) * 4;
    int tx0 = (tile & 7) * 8;
    int tid = threadIdx.x;
    int lane = tid & 63, wave = tid >> 6;
    int q = lane >> 4, m = lane & 15;

    // ---- preload phase-B B-frags (w1) + BN pair ----
    int bnt = wave >> 2;
    int bo  = bnt * 16 + m;
    const __hip_bfloat16* w1b = (const __hip_bfloat16*)(ws + OFF_W1B);
    short8 bw[4];
    #pragma unroll
    for (int s = 0; s < 4; ++s)
        bw[s] = *(const short8*)(w1b + bo * 128 + s * 32 + q * 8);
    float2 bnia = ((const float2*)(ws + OFF_BN))[bo];

    for (int rep = 0; rep < 2; ++rep) {   // DIAGNOSTIC rep-loop (idempotent)

    // ---- phase A: copy x 8x12 halo (bf16, pre-transposed) -> xs, b128 in/out ----
    const __hip_bfloat16* xg = (const __hip_bfloat16*)(ws + OFF_XG) + (size_t)b * 16 * 4096 * 8;
    #pragma unroll
    for (int it = 0; it < 2; ++it) {
        int idx = tid + it * 1024;
        if (idx < 1536) {
            int cq = idx / 96, p = idx - cq * 96;
            int hy = p / 12, hx = p - hy * 12;
            int gy = ty0 + hy - 2, gx = tx0 + hx - 2;
            short8 v;
            #pragma unroll
            for (int j = 0; j < 8; ++j) v[j] = 0;
            if ((unsigned)gy < 64u && (unsigned)gx < 64u)
                v = *(const short8*)(xg + ((size_t)cq * 4096 + gy * 64 + gx) * 8);
            *(short8*)(&xs[idx * 8]) = v;
        }
    }
    __syncthreads();

    // ---- phase B: h = relu(bn(w1 @ x)) via MFMA: M=60 halo pix, N=64, K=128 ----
    {
        int mt = wave & 3;
        int hp = mt * 16 + m;
        int hy1 = hp / 10, hx1 = hp - hy1 * 10;
        int xrow = (hy1 + 1) * 12 + (hx1 + 1);
        floatx4 acc;
        #pragma unroll
        for (int r = 0; r < 4; ++r) acc[r] = 0.f;
        #pragma unroll
        for (int s = 0; s < 4; ++s) {
            short8 a = *(const short8*)(&xs[((s * 4 + q) * 96 + xrow) * 8]);
            acc = __builtin_amdgcn_mfma_f32_16x16x32_bf16(a, bw[s], acc, 0, 0, 0);
        }
        #pragma unroll
        for (int r = 0; r < 4; ++r) {
            int prow = mt * 16 + q * 4 + r;
            if (prow < 60) {
                int phy = prow / 10, phx = prow - phy * 10;
                int gy = ty0 + phy - 1, gx = tx0 + phx - 1;
                bool in = ((unsigned)gy < 64u) && ((unsigned)gx < 64u);
                float v = in ? fmaxf(fmaf(acc[r], bnia.x, bnia.y), 0.f) : 0.f;
                hs[prow * 72 + bo] = __float2bfloat16(v);
            }
        }
    }
    __syncthreads();

    // ---- phase C: 3x3 conv via MFMA: M=32 pix, N=112, K=576 ----
    {
        int mt = wave & 1, nt = wave >> 1;
        if (nt < 7) {
            int pixidx = mt * 16 + m;
            int py = pixidx >> 3, px = pixidx & 7;
            const __hip_bfloat16* w2b = (const __hip_bfloat16*)(ws + OFF_W2B);
            const __hip_bfloat16* bp  = w2b + (size_t)(nt * 16 + m) * 576 + q * 8;

            floatx4 acc;
            #pragma unroll
            for (int r = 0; r < 4; ++r) acc[r] = 0.f;

            short8 bcur = *(const short8*)bp;
            for (int s = 0; s < 18; ++s) {
                int t = s >> 1, c0 = (s & 1) * 32;
                int ti = t / 3, tj = t - ti * 3;
                short8 a = *(const short8*)(&hs[((py + ti) * 10 + px + tj) * 72 + c0 + q * 8]);
                short8 bn2 = bcur;
                if (s < 17) bn2 = *(const short8*)(bp + (s + 1) * 32);
                acc = __builtin_amdgcn_mfma_f32_16x16x32_bf16(a, bcur, acc, 0, 0, 0);
                bcur = bn2;
            }
            #pragma unroll
            for (int r = 0; r < 4; ++r)
                lg[(mt * 16 + q * 4 + r) * 114 + nt * 16 + m] = acc[r];
        }
    }
    __syncthreads();

    // ---- phase D: softmax over 25 taps -> ks [t*4+g][pix] ----
    if (tid < 128) {
        int pix = tid & 31, g = tid >> 5;
        float v[25];
        #pragma unroll
        for (int wi = 0; wi < 25; ++wi) v[wi] = lg[pix * 114 + g * 25 + wi];
        float mx = v[0];
        #pragma unroll
        for (int wi = 1; wi < 25; ++wi) mx = fmaxf(mx, v[wi]);
        float ssum = 0.f;
        #pragma unroll
        for (int wi = 0; wi < 25; ++wi) { v[wi] = __expf(v[wi] - mx); ssum += v[wi]; }
        float rs = 1.f / ssum;
        #pragma unroll
        for (int t25 = 0; t25 < 25; ++t25)
            ks[(t25 * 4 + g) * 33 + pix] = v[t25] * rs;
    }
    __syncthreads();

    // ---- phase E: 5x5 reassembly + pixel shuffle ----
    {
        int pix   = lane & 31;
        int chunk = lane >> 5;
        int co    = wave;
        int py = pix >> 3, px = pix & 7;
        int Y = ty0 + py, X = tx0 + px;

        float acc[16];  // [8 ch][2 g]
        #pragma unroll
        for (int i = 0; i < 16; ++i) acc[i] = 0.f;

        const __hip_bfloat16* xsb = xs + (size_t)co * 96 * 8;
        #pragma unroll 5
        for (int t = 0; t < 25; ++t) {
            int ti = t / 5, tj = t - ti * 5;
            int xrow = (py + ti) * 12 + (px + tj);
            union { short8 s; unsigned u[4]; } xv;
            xv.s = *(const short8*)(xsb + xrow * 8);
            float k0 = ks[(t * 4 + chunk * 2 + 0) * 33 + pix];
            float k1 = ks[(t * 4 + chunk * 2 + 1) * 33 + pix];
            #pragma unroll
            for (int j = 0; j < 4; ++j) {
                float xa = bfbits(xv.u[j] << 16);
                float xb2 = bfbits(xv.u[j] & 0xFFFF0000u);
                acc[(j * 2 + 0) * 2 + 0] = fmaf(xa,  k0, acc[(j * 2 + 0) * 2 + 0]);
                acc[(j * 2 + 0) * 2 + 1] = fmaf(xa,  k1, acc[(j * 2 + 0) * 2 + 1]);
                acc[(j * 2 + 1) * 2 + 0] = fmaf(xb2, k0, acc[(j * 2 + 1) * 2 + 0]);
                acc[(j * 2 + 1) * 2 + 1] = fmaf(xb2, k1, acc[(j * 2 + 1) * 2 + 1]);
            }
        }

        #pragma unroll
        for (int i = 0; i < 8; ++i) {
            size_t o0 = (((size_t)b * 128 + co * 8 + i) * 128 + 2 * Y + chunk) * 128 + 2 * X;
            *(float2*)(out + o0) = make_float2(acc[i * 2 + 0], acc[i * 2 + 1]);
        }
    }
    __syncthreads();   // separate reps cleanly

    }  // rep
}

extern "C" void kernel_launch(void* const* d_in, const int* in_sizes, int n_in,
                              void* d_out, int out_size, void* d_ws, size_t ws_size,
                              hipStream_t stream) {
    const float* x     = (const float*)d_in[0];
    const float* w1    = (const float*)d_in[1];
    const float* w2    = (const float*)d_in[2];
    const float* gamma = (const float*)d_in[3];
    const float* beta  = (const float*)d_in[4];
    const float* mean  = (const float*)d_in[5];
    const float* var   = (const float*)d_in[6];
    float* out = (float*)d_out;
    char*  ws  = (char*)d_ws;

    prep_kernel<<<1309, 256, 0, stream>>>(x, w1, w2, gamma, beta, mean, var, ws);
    fused_carafe<<<512, 1024, 0, stream>>>(ws, out);
}

// Round 10
// 101.998 us; speedup vs baseline: 1.4787x; 1.4787x over previous
//
#include <hip/hip_runtime.h>
#include <hip/hip_bf16.h>

// CARAFE fused: B=4, C=128, H=W=64, C_MID=64, S=2, K=5
// Round 10: 512-thread blocks, __launch_bounds__(512,4) -> 128 VGPR cap, NO scratch
// spills (round-9 diagnostic showed (1024,8) forced VGPR=32 + ~80MB spill traffic).
// 2 blocks/CU via LDS 61KB; 8 waves/block each doing 2x per-wave work.
#define HW 4096

typedef __attribute__((ext_vector_type(8))) short  short8;   // 8 bf16 (4 VGPRs)
typedef __attribute__((ext_vector_type(4))) float  floatx4;  // MFMA C/D

// workspace (BYTE offsets)
#define OFF_W2B 0ul        // bf16 [112][576]  = 129024 B   w2b[n][k], k = tap*64 + c
#define OFF_W1B 129024ul   // bf16 [64][128]   = 16384 B    w1b[o][c]
#define OFF_BN  145408ul   // float2[64]       = 512 B      (inv, add) per o
#define OFF_XG  145920ul   // bf16 [4][16][4096][8] = 4 MB  x transposed: [b][cq][pix][8c]

__device__ __forceinline__ float bfbits(unsigned u) {
    union { unsigned u; float f; } t; t.u = u; return t.f;
}

// ---------------- prep: x -> bf16 [b][cq][pix][8]; w2 -> bf16 [n][k]; w1 bf16; BN folded ----
__global__ __launch_bounds__(256) void prep_kernel(const float* __restrict__ x,
                                                   const float* __restrict__ w1,
                                                   const float* __restrict__ w2,
                                                   const float* __restrict__ gamma,
                                                   const float* __restrict__ beta,
                                                   const float* __restrict__ mean,
                                                   const float* __restrict__ var,
                                                   char* __restrict__ ws) {
    int tid = blockIdx.x * 256 + threadIdx.x;
    if (tid < 262144) {
        int pix = tid & 4095;
        int cq  = (tid >> 12) & 15;
        int b   = tid >> 16;
        const float* xp = x + ((size_t)(b * 128 + cq * 8)) * HW + pix;
        union { short8 s; __hip_bfloat16 h[8]; } u;
        #pragma unroll
        for (int cc = 0; cc < 8; ++cc) u.h[cc] = __float2bfloat16(xp[(size_t)cc * HW]);
        *(short8*)((__hip_bfloat16*)(ws + OFF_XG) + (size_t)tid * 8) = u.s;
        return;
    }
    int t2 = tid - 262144;
    if (t2 < 64512) {
        int n = t2 / 576;
        int k = t2 - n * 576;        // k = tap*64 + c
        int t = k >> 6, c = k & 63;
        float v = (n < 100) ? w2[(n * 64 + c) * 9 + t] : 0.f;
        ((__hip_bfloat16*)(ws + OFF_W2B))[t2] = __float2bfloat16(v);
    } else if (t2 < 64512 + 8192) {
        int i = t2 - 64512;
        ((__hip_bfloat16*)(ws + OFF_W1B))[i] = __float2bfloat16(w1[i]);
    } else if (t2 < 64512 + 8192 + 64) {
        int o = t2 - 64512 - 8192;
        float inv = gamma[o] * rsqrtf(var[o] + 1e-5f);
        ((float2*)(ws + OFF_BN))[o] = make_float2(inv, beta[o] - mean[o] * inv);
    }
}

// ---------------- fused CARAFE: one block per (b, 4x8 tile), 512 threads = 8 waves ----------
__global__ __launch_bounds__(512, 4) void fused_carafe(const char* __restrict__ ws,
                                                       float* __restrict__ out) {
    __shared__ __align__(16) __hip_bfloat16 xs[1536 * 8];  // x halo [cq16][pix96][8c], 24.6 KB
    __shared__ __align__(16) __hip_bfloat16 hs[60 * 72];   // h halo 6x10 [pix][c],      8.6 KB
    __shared__ __align__(16) float lg[32 * 114];           // logits [pix][n],          14.6 KB
    __shared__ __align__(16) float ks[100 * 33];           // ker [t*4+g][pix],         13.2 KB

    int b    = blockIdx.x >> 7;
    int tile = blockIdx.x & 127;
    int ty0 = (tile >> 3) * 4;
    int tx0 = (tile & 7) * 8;
    int tid = threadIdx.x;
    int lane = tid & 63, wave = tid >> 6;   // 8 waves
    int q = lane >> 4, m = lane & 15;

    // ---- preload phase-B B-frags (w1) + BN pair (per-wave nt = wave&3) ----
    int bnt = wave & 3;
    int bo  = bnt * 16 + m;
    const __hip_bfloat16* w1b = (const __hip_bfloat16*)(ws + OFF_W1B);
    short8 bw[4];
    #pragma unroll
    for (int s = 0; s < 4; ++s)
        bw[s] = *(const short8*)(w1b + bo * 128 + s * 32 + q * 8);
    float2 bnia = ((const float2*)(ws + OFF_BN))[bo];

    // ---- phase A: copy x 8x12 halo (bf16, pre-transposed) -> xs, b128 in/out ----
    const __hip_bfloat16* xg = (const __hip_bfloat16*)(ws + OFF_XG) + (size_t)b * 16 * 4096 * 8;
    #pragma unroll
    for (int it = 0; it < 3; ++it) {
        int idx = tid + it * 512;             // 1536 = 3 * 512
        int cq = idx / 96, p = idx - cq * 96;
        int hy = p / 12, hx = p - hy * 12;
        int gy = ty0 + hy - 2, gx = tx0 + hx - 2;
        short8 v;
        #pragma unroll
        for (int j = 0; j < 8; ++j) v[j] = 0;
        if ((unsigned)gy < 64u && (unsigned)gx < 64u)
            v = *(const short8*)(xg + ((size_t)cq * 4096 + gy * 64 + gx) * 8);
        *(short8*)(&xs[idx * 8]) = v;
    }
    __syncthreads();

    // ---- phase B: h = relu(bn(w1 @ x)) via MFMA: M=60 halo pix, N=64, K=128 ----
    // wave = (mt2 = wave>>2, nt = wave&3); each wave does mt = mt2*2, mt2*2+1
    #pragma unroll
    for (int mi = 0; mi < 2; ++mi) {
        int mt = (wave >> 2) * 2 + mi;
        int hp = mt * 16 + m;
        int hy1 = hp / 10, hx1 = hp - hy1 * 10;
        int xrow = (hy1 + 1) * 12 + (hx1 + 1);
        floatx4 acc;
        #pragma unroll
        for (int r = 0; r < 4; ++r) acc[r] = 0.f;
        #pragma unroll
        for (int s = 0; s < 4; ++s) {
            short8 a = *(const short8*)(&xs[((s * 4 + q) * 96 + xrow) * 8]);
            acc = __builtin_amdgcn_mfma_f32_16x16x32_bf16(a, bw[s], acc, 0, 0, 0);
        }
        #pragma unroll
        for (int r = 0; r < 4; ++r) {
            int prow = mt * 16 + q * 4 + r;
            if (prow < 60) {
                int phy = prow / 10, phx = prow - phy * 10;
                int gy = ty0 + phy - 1, gx = tx0 + phx - 1;
                bool in = ((unsigned)gy < 64u) && ((unsigned)gx < 64u);
                float v = in ? fmaxf(fmaf(acc[r], bnia.x, bnia.y), 0.f) : 0.f;
                hs[prow * 72 + bo] = __float2bfloat16(v);
            }
        }
    }
    __syncthreads();

    // ---- phase C: 3x3 conv via MFMA: M=32 pix, N=112, K=576; 14 tasks over 8 waves ----
    for (int task = wave; task < 14; task += 8) {
        int mt = task & 1, nt = task >> 1;
        int pixidx = mt * 16 + m;
        int py = pixidx >> 3, px = pixidx & 7;
        const __hip_bfloat16* w2b = (const __hip_bfloat16*)(ws + OFF_W2B);
        const __hip_bfloat16* bp  = w2b + (size_t)(nt * 16 + m) * 576 + q * 8;

        floatx4 acc;
        #pragma unroll
        for (int r = 0; r < 4; ++r) acc[r] = 0.f;

        short8 bcur = *(const short8*)bp;
        for (int s = 0; s < 18; ++s) {
            int t = s >> 1, c0 = (s & 1) * 32;
            int ti = t / 3, tj = t - ti * 3;
            short8 a = *(const short8*)(&hs[((py + ti) * 10 + px + tj) * 72 + c0 + q * 8]);
            short8 bn2 = bcur;
            if (s < 17) bn2 = *(const short8*)(bp + (s + 1) * 32);
            acc = __builtin_amdgcn_mfma_f32_16x16x32_bf16(a, bcur, acc, 0, 0, 0);
            bcur = bn2;
        }
        #pragma unroll
        for (int r = 0; r < 4; ++r)
            lg[(mt * 16 + q * 4 + r) * 114 + nt * 16 + m] = acc[r];
    }
    __syncthreads();

    // ---- phase D: softmax over 25 taps -> ks [t*4+g][pix] ----
    if (tid < 128) {
        int pix = tid & 31, g = tid >> 5;
        float v[25];
        #pragma unroll
        for (int wi = 0; wi < 25; ++wi) v[wi] = lg[pix * 114 + g * 25 + wi];
        float mx = v[0];
        #pragma unroll
        for (int wi = 1; wi < 25; ++wi) mx = fmaxf(mx, v[wi]);
        float ssum = 0.f;
        #pragma unroll
        for (int wi = 0; wi < 25; ++wi) { v[wi] = __expf(v[wi] - mx); ssum += v[wi]; }
        float rs = 1.f / ssum;
        #pragma unroll
        for (int t25 = 0; t25 < 25; ++t25)
            ks[(t25 * 4 + g) * 33 + pix] = v[t25] * rs;
    }
    __syncthreads();

    // ---- phase E: 5x5 reassembly + pixel shuffle; 16 ch-octs over 8 waves ----
    {
        int pix   = lane & 31;
        int chunk = lane >> 5;                // 0 -> rows 2Y (g0,g1), 1 -> rows 2Y+1 (g2,g3)
        int py = pix >> 3, px = pix & 7;
        int Y = ty0 + py, X = tx0 + px;

        for (int co = wave; co < 16; co += 8) {
            float acc[16];  // [8 ch][2 g]
            #pragma unroll
            for (int i = 0; i < 16; ++i) acc[i] = 0.f;

            const __hip_bfloat16* xsb = xs + (size_t)co * 96 * 8;
            #pragma unroll 5
            for (int t = 0; t < 25; ++t) {
                int ti = t / 5, tj = t - ti * 5;
                int xrow = (py + ti) * 12 + (px + tj);
                union { short8 s; unsigned u[4]; } xv;
                xv.s = *(const short8*)(xsb + xrow * 8);
                float k0 = ks[(t * 4 + chunk * 2 + 0) * 33 + pix];
                float k1 = ks[(t * 4 + chunk * 2 + 1) * 33 + pix];
                #pragma unroll
                for (int j = 0; j < 4; ++j) {
                    float xa  = bfbits(xv.u[j] << 16);
                    float xb2 = bfbits(xv.u[j] & 0xFFFF0000u);
                    acc[(j * 2 + 0) * 2 + 0] = fmaf(xa,  k0, acc[(j * 2 + 0) * 2 + 0]);
                    acc[(j * 2 + 0) * 2 + 1] = fmaf(xa,  k1, acc[(j * 2 + 0) * 2 + 1]);
                    acc[(j * 2 + 1) * 2 + 0] = fmaf(xb2, k0, acc[(j * 2 + 1) * 2 + 0]);
                    acc[(j * 2 + 1) * 2 + 1] = fmaf(xb2, k1, acc[(j * 2 + 1) * 2 + 1]);
                }
            }

            #pragma unroll
            for (int i = 0; i < 8; ++i) {
                size_t o0 = (((size_t)b * 128 + co * 8 + i) * 128 + 2 * Y + chunk) * 128 + 2 * X;
                *(float2*)(out + o0) = make_float2(acc[i * 2 + 0], acc[i * 2 + 1]);
            }
        }
    }
}

extern "C" void kernel_launch(void* const* d_in, const int* in_sizes, int n_in,
                              void* d_out, int out_size, void* d_ws, size_t ws_size,
                              hipStream_t stream) {
    const float* x     = (const float*)d_in[0];
    const float* w1    = (const float*)d_in[1];
    const float* w2    = (const float*)d_in[2];
    const float* gamma = (const float*)d_in[3];
    const float* beta  = (const float*)d_in[4];
    const float* mean  = (const float*)d_in[5];
    const float* var   = (const float*)d_in[6];
    float* out = (float*)d_out;
    char*  ws  = (char*)d_ws;

    prep_kernel<<<1309, 256, 0, stream>>>(x, w1, w2, gamma, beta, mean, var, ws);
    fused_carafe<<<512, 512, 0, stream>>>(ws, out);
}